// Round 11
// baseline (142.606 us; speedup 1.0000x reference)
//
#include <hip/hip_runtime.h>
#include <hip/hip_bf16.h>
#include <math.h>

#define BS 4096
#define DIM 2048
#define EPSV 1e-6f

typedef unsigned short u16;
typedef float f32x4 __attribute__((ext_vector_type(4)));
typedef __bf16 bf16x8 __attribute__((ext_vector_type(8)));

__device__ inline u16 f2bf(float f) {
  unsigned u = __float_as_uint(f);
  unsigned r = (u + 0x7fffu + ((u >> 16) & 1u)) >> 16;
  return (u16)r;
}

__device__ inline void gload16(const u16* g, u16* l) {
  __builtin_amdgcn_global_load_lds((const __attribute__((address_space(1))) unsigned int*)g,
                                   (__attribute__((address_space(3))) unsigned int*)l,
                                   16, 0, 0);
}

// ---------------- prep: f32 -> bf16 copies + per-row sum / sumsq ----------------
__global__ __launch_bounds__(256) void prep_kernel(
    const float* __restrict__ h1, const float* __restrict__ h2,
    u16* __restrict__ A, u16* __restrict__ B,
    float* __restrict__ sq1, float* __restrict__ s1,
    float* __restrict__ sq2, float* __restrict__ s2) {
  int b = blockIdx.x;
  const float* src; u16* dst; float* sqo; float* so; int row;
  if (b < BS) { src = h1; dst = A; sqo = sq1; so = s1; row = b; }
  else        { src = h2; dst = B; sqo = sq2; so = s2; row = b - BS; }
  src += (size_t)row * DIM;
  dst += (size_t)row * DIM;
  int t = threadIdx.x;
  float sq = 0.f, s = 0.f;
#pragma unroll
  for (int it = 0; it < DIM / (256 * 4); ++it) {
    int idx = (it * 256 + t) * 4;
    float4 v = *(const float4*)(src + idx);
    sq += v.x * v.x + v.y * v.y + v.z * v.z + v.w * v.w;
    s  += v.x + v.y + v.z + v.w;
    ushort4 o;
    o.x = f2bf(v.x); o.y = f2bf(v.y); o.z = f2bf(v.z); o.w = f2bf(v.w);
    *(ushort4*)(dst + idx) = o;
  }
#pragma unroll
  for (int m = 32; m; m >>= 1) { sq += __shfl_xor(sq, m, 64); s += __shfl_xor(s, m, 64); }
  __shared__ float lsq[4], ls[4];
  if ((t & 63) == 0) { lsq[t >> 6] = sq; ls[t >> 6] = s; }
  __syncthreads();
  if (t == 0) {
    sqo[row] = lsq[0] + lsq[1] + lsq[2] + lsq[3];
    so[row]  = ls[0] + ls[1] + ls[2] + ls[3];
  }
}

// ---------------- GEMM: 128x128 tile, 4 waves, cross-tile register pipeline ----------------
// 256 threads = 4 waves (2x2), wave tile 64x64. LDS 2 slots x 16KB = 32 KB ->
// 3 blocks/CU at <=170 VGPR (__launch_bounds__(256,3)).
// Region kt: MFMA tile kt FROM REGISTERS while reading tile kt+1's frags from
// LDS (independent -> compiler interleaves; LDS hides under MFMA) and staging
// tile kt+2 into slot[kt&1] (its reads were certified by the barrier entering
// this region). 2 slots suffice; <=4 gloads in flight at each __syncthreads,
// issued a full region earlier (drain ~free). Zero-conflict swizzle (R7-verified).
#define BK 32
#define NT (DIM / BK)

__global__ __launch_bounds__(256, 3) void gemm_select_kernel(
    const u16* __restrict__ A, const u16* __restrict__ B,
    const float* __restrict__ sq1, const float* __restrict__ s1,
    const float* __restrict__ sq2, const float* __restrict__ s2,
    const int* __restrict__ lab1, const int* __restrict__ lab2,
    float4* __restrict__ part) {
  __shared__ __align__(16) u16 lds[2][8192];  // per slot: A 128x32 (4096 u16) + B 128x32
  int tid = threadIdx.x;
  int w = tid >> 6, l = tid & 63;
  int wr = w >> 1, wc = w & 1;
  int g = l >> 4, c = l & 15;
  int by = blockIdx.x >> 5, bx = blockIdx.x & 31;
  const int rowB = by * 128, colB = bx * 128;

  // staging: pre-swizzled global source, linear LDS dest (rule #21)
  // unit idx = q*256+tid -> row = q*64 + (tid>>2); (row>>1)&3 == (tid>>3)&3 (q*32%4==0)
  int srow = tid >> 2;
  int schunk = (tid & 3) ^ ((tid >> 3) & 3);
  const u16* gA0 = A + (size_t)(rowB + srow) * DIM + schunk * 8;
  const u16* gA1 = gA0 + (size_t)64 * DIM;
  const u16* gB0 = B + (size_t)(colB + srow) * DIM + schunk * 8;
  const u16* gB1 = gB0 + (size_t)64 * DIM;

#define STAGE(T, SL) do { size_t k_ = (size_t)(T) * BK;   \
    gload16(gA0 + k_, &lds[SL][0]    + tid * 8);          \
    gload16(gA1 + k_, &lds[SL][2048] + tid * 8);          \
    gload16(gB0 + k_, &lds[SL][4096] + tid * 8);          \
    gload16(gB1 + k_, &lds[SL][6144] + tid * 8); } while (0)

  // fragment reads (swizzled): u16 idx = row*32 + (g ^ ((c>>1)&3))*8
  const int xc = (g ^ ((c >> 1) & 3)) * 8;

#define READ(AF, BF, SL) do {                                                     \
    _Pragma("unroll") for (int mi_ = 0; mi_ < 4; ++mi_)                           \
      AF[mi_] = *(const bf16x8*)&lds[SL][(wr * 64 + mi_ * 16 + c) * 32 + xc];     \
    _Pragma("unroll") for (int ni_ = 0; ni_ < 4; ++ni_)                           \
      BF[ni_] = *(const bf16x8*)&lds[SL][4096 + (wc * 64 + ni_ * 16 + c) * 32 + xc]; } while (0)

#define MMAC(AF, BF) do {                                                         \
    _Pragma("unroll") for (int mi_ = 0; mi_ < 4; ++mi_)                           \
      _Pragma("unroll") for (int ni_ = 0; ni_ < 4; ++ni_)                         \
        acc[mi_][ni_] = __builtin_amdgcn_mfma_f32_16x16x32_bf16(                  \
            AF[mi_], BF[ni_], acc[mi_][ni_], 0, 0, 0); } while (0)

  f32x4 acc[4][4] = {};
  bf16x8 a0[4], b0[4], a1[4], b1[4];

  // prologue: stage tiles 0,1; read tile 0 frags; certify slot0 reads done
  STAGE(0, 0); STAGE(1, 1);
  __syncthreads();
  READ(a0, b0, 0);
  __syncthreads();

  for (int kt = 0; kt < NT; kt += 2) {
    // region kt: stage kt+2 -> slot0 (reads certified), read kt+1 frags, MFMA kt
    if (kt + 2 < NT) STAGE(kt + 2, 0);
    READ(a1, b1, 1);
    MMAC(a0, b0);
    __syncthreads();
    // region kt+1: stage kt+3 -> slot1, read kt+2 frags, MFMA kt+1
    if (kt + 3 < NT) STAGE(kt + 3, 1);
    if (kt + 2 < NT) READ(a0, b0, 0);
    MMAC(a1, b1);
    __syncthreads();
  }
#undef STAGE
#undef READ
#undef MMAC

  // --- epilogue: dist + fused hard-pos/neg partial select ---
  float pc_[4]; int l2v[4]; int jcol[4];
#pragma unroll
  for (int ni = 0; ni < 4; ++ni) {
    int j = colB + wc * 64 + ni * 16 + c;
    jcol[ni] = j;
    l2v[ni] = lab2[j];
    pc_[ni] = sq2[j] - 2.0f * EPSV * s2[j];
  }
  const float cst = (float)DIM * EPSV * EPSV;
  int partCol = bx * 2 + wc;

#pragma unroll
  for (int mi = 0; mi < 4; ++mi) {
    float posV[4], negV[4]; int posI[4], negI[4];
    float pr[4]; int l1v[4];
#pragma unroll
    for (int r = 0; r < 4; ++r) {
      int i = rowB + wr * 64 + mi * 16 + g * 4 + r;
      l1v[r] = lab1[i];
      pr[r] = sq1[i] + 2.0f * EPSV * s1[i] + cst;
      posV[r] = -3.0e38f; posI[r] = 0x7fffffff;
      negV[r] =  3.0e38f; negI[r] = 0x7fffffff;
    }
#pragma unroll
    for (int ni = 0; ni < 4; ++ni) {
#pragma unroll
      for (int r = 0; r < 4; ++r) {
        float dot = acc[mi][ni][r];
        float d2 = pr[r] + pc_[ni] - 2.0f * dot;
        float dist = sqrtf(fmaxf(d2, 0.0f));
        bool same = (l1v[r] == l2v[ni]);
        float pv = same ? dist : -3.0e38f;
        float nv = same ?  3.0e38f : dist;
        if (pv > posV[r] || (pv == posV[r] && jcol[ni] < posI[r])) { posV[r] = pv; posI[r] = jcol[ni]; }
        if (nv < negV[r] || (nv == negV[r] && jcol[ni] < negI[r])) { negV[r] = nv; negI[r] = jcol[ni]; }
      }
    }
#pragma unroll
    for (int m = 1; m < 16; m <<= 1) {
#pragma unroll
      for (int r = 0; r < 4; ++r) {
        float ov = __shfl_xor(posV[r], m, 64);
        int   oi = __shfl_xor(posI[r], m, 64);
        if (ov > posV[r] || (ov == posV[r] && oi < posI[r])) { posV[r] = ov; posI[r] = oi; }
        float nv2 = __shfl_xor(negV[r], m, 64);
        int   on  = __shfl_xor(negI[r], m, 64);
        if (nv2 < negV[r] || (nv2 == negV[r] && on < negI[r])) { negV[r] = nv2; negI[r] = on; }
      }
    }
    if (c == 0) {
#pragma unroll
      for (int r = 0; r < 4; ++r) {
        int i = rowB + wr * 64 + mi * 16 + g * 4 + r;
        float4 o;
        o.x = posV[r]; o.y = __int_as_float(posI[r]);
        o.z = negV[r]; o.w = __int_as_float(negI[r]);
        part[(size_t)i * 64 + partCol] = o;
      }
    }
  }
}

// ---------------- combine 64 partials per row -> per-row loss directly ----------------
// posV/negV ARE d_ap/d_an (same expanded ||x-y+eps|| formula as reference).
__global__ __launch_bounds__(256) void reduce_kernel(const float4* __restrict__ part,
                                                     float* __restrict__ perrow,
                                                     float* __restrict__ validf) {
  int row = blockIdx.x * 4 + (threadIdx.x >> 6);
  int lane = threadIdx.x & 63;
  float4 p = part[(size_t)row * 64 + lane];
  float posV = p.x; int posI = __float_as_int(p.y);
  float negV = p.z; int negI = __float_as_int(p.w);
#pragma unroll
  for (int m = 1; m < 64; m <<= 1) {
    float ov = __shfl_xor(posV, m, 64);
    int   oi = __shfl_xor(posI, m, 64);
    if (ov > posV || (ov == posV && oi < posI)) { posV = ov; posI = oi; }
    float nv = __shfl_xor(negV, m, 64);
    int   on = __shfl_xor(negI, m, 64);
    if (nv < negV || (nv == negV && on < negI)) { negV = nv; negI = on; }
  }
  if (lane == 0) {
    bool valid = (posV > -1.0e38f && negV < 1.0e38f);
    perrow[row] = valid ? fmaxf(posV - negV, 0.0f) : 0.0f;
    validf[row] = valid ? 1.0f : 0.0f;
  }
}

// ---------------- deterministic finalize (fixed-order tree) ----------------
__global__ __launch_bounds__(256) void finalize_kernel(const float* __restrict__ perrow,
                                                       const float* __restrict__ validf,
                                                       float* __restrict__ out) {
  int t = threadIdx.x;
  float s = 0.f, cv = 0.f;
  for (int i = t; i < BS; i += 256) { s += perrow[i]; cv += validf[i]; }
  __shared__ float ls[256], lc[256];
  ls[t] = s; lc[t] = cv;
  __syncthreads();
  for (int m = 128; m; m >>= 1) {
    if (t < m) { ls[t] += ls[t + m]; lc[t] += lc[t + m]; }
    __syncthreads();
  }
  if (t == 0) out[0] = (lc[0] > 0.f) ? ls[0] / fmaxf(lc[0], 1.f) : 0.f;
}

extern "C" void kernel_launch(void* const* d_in, const int* in_sizes, int n_in,
                              void* d_out, int out_size, void* d_ws, size_t ws_size,
                              hipStream_t stream) {
  const float* h1 = (const float*)d_in[0];
  const float* h2 = (const float*)d_in[1];
  const int* lab1 = (const int*)d_in[2];
  const int* lab2 = (const int*)d_in[3];

  char* ws = (char*)d_ws;
  u16* A = (u16*)ws;
  u16* B = (u16*)(ws + (size_t)BS * DIM * 2);
  size_t off = (size_t)BS * DIM * 4;
  float* sq1 = (float*)(ws + off); off += BS * 4;
  float* s1  = (float*)(ws + off); off += BS * 4;
  float* sq2 = (float*)(ws + off); off += BS * 4;
  float* s2  = (float*)(ws + off); off += BS * 4;
  float4* part = (float4*)(ws + off); off += (size_t)BS * 64 * 16;
  float* perrow = (float*)(ws + off); off += BS * 4;
  float* validf = (float*)(ws + off); off += BS * 4;

  prep_kernel<<<2 * BS, 256, 0, stream>>>(h1, h2, A, B, sq1, s1, sq2, s2);
  gemm_select_kernel<<<1024, 256, 0, stream>>>(A, B, sq1, s1, sq2, s2, lab1, lab2, part);
  reduce_kernel<<<BS / 4, 256, 0, stream>>>(part, perrow, validf);
  finalize_kernel<<<1, 256, 0, stream>>>(perrow, validf, (float*)d_out);
}

// Round 12
// 117.858 us; speedup vs baseline: 1.2100x; 1.2100x over previous
//
#include <hip/hip_runtime.h>
#include <hip/hip_bf16.h>
#include <math.h>

#define BS 4096
#define DIM 2048
#define EPSV 1e-6f

typedef unsigned short u16;
typedef float f32x4 __attribute__((ext_vector_type(4)));
typedef __bf16 bf16x8 __attribute__((ext_vector_type(8)));

__device__ inline u16 f2bf(float f) {
  unsigned u = __float_as_uint(f);
  unsigned r = (u + 0x7fffu + ((u >> 16) & 1u)) >> 16;
  return (u16)r;
}

__device__ inline void gload16(const u16* g, u16* l) {
  __builtin_amdgcn_global_load_lds((const __attribute__((address_space(1))) unsigned int*)g,
                                   (__attribute__((address_space(3))) unsigned int*)l,
                                   16, 0, 0);
}

// ---------------- prep: f32 -> bf16 copies + per-row sum / sumsq ----------------
__global__ __launch_bounds__(256) void prep_kernel(
    const float* __restrict__ h1, const float* __restrict__ h2,
    u16* __restrict__ A, u16* __restrict__ B,
    float* __restrict__ sq1, float* __restrict__ s1,
    float* __restrict__ sq2, float* __restrict__ s2) {
  int b = blockIdx.x;
  const float* src; u16* dst; float* sqo; float* so; int row;
  if (b < BS) { src = h1; dst = A; sqo = sq1; so = s1; row = b; }
  else        { src = h2; dst = B; sqo = sq2; so = s2; row = b - BS; }
  src += (size_t)row * DIM;
  dst += (size_t)row * DIM;
  int t = threadIdx.x;
  float sq = 0.f, s = 0.f;
#pragma unroll
  for (int it = 0; it < DIM / (256 * 4); ++it) {
    int idx = (it * 256 + t) * 4;
    float4 v = *(const float4*)(src + idx);
    sq += v.x * v.x + v.y * v.y + v.z * v.z + v.w * v.w;
    s  += v.x + v.y + v.z + v.w;
    ushort4 o;
    o.x = f2bf(v.x); o.y = f2bf(v.y); o.z = f2bf(v.z); o.w = f2bf(v.w);
    *(ushort4*)(dst + idx) = o;
  }
#pragma unroll
  for (int m = 32; m; m >>= 1) { sq += __shfl_xor(sq, m, 64); s += __shfl_xor(s, m, 64); }
  __shared__ float lsq[4], ls[4];
  if ((t & 63) == 0) { lsq[t >> 6] = sq; ls[t >> 6] = s; }
  __syncthreads();
  if (t == 0) {
    sqo[row] = lsq[0] + lsq[1] + lsq[2] + lsq[3];
    so[row]  = ls[0] + ls[1] + ls[2] + ls[3];
  }
}

// ---------------- GEMM: 256x128 tile (R10 geometry), 3-buffer rotation, B-prefetch ----------------
// 512 threads = 8 waves (4M x 2N), wave tile 64x64, acc[4][4]=64 regs.
// LDS 3 x 24KB = 72KB -> 2 blocks/CU (144KB). VGPR: acc64 + a16 + bA16 + bB16 = 112.
// Region kt: stage kt+2 -> buf[(kt+2)%3]; read A(kt); PREFETCH B(kt+1) (overlaps
// MFMA since MFMA(kt) doesn't consume it); MFMA(a, b_cur); __syncthreads (drains
// vmcnt -> tile kt+2 landed; lgkmcnt -> all reads done before any overwrite).
// Hazards: buf m overwritten 2 regions after its last reader's drain. Zero-conflict
// swizzle chunk^=(row>>1)&3 (R7-verified, conflicts=0).
#define BK 32
#define NT (DIM / BK)

__global__ __launch_bounds__(512, 4) void gemm_select_kernel(
    const u16* __restrict__ A, const u16* __restrict__ B,
    const float* __restrict__ sq1, const float* __restrict__ s1,
    const float* __restrict__ sq2, const float* __restrict__ s2,
    const int* __restrict__ lab1, const int* __restrict__ lab2,
    float4* __restrict__ part) {
  __shared__ __align__(16) u16 lds[3][12288];  // per buf: A 256x32 (8192 u16) + B 128x32 (4096)
  int tid = threadIdx.x;
  int w = tid >> 6, l = tid & 63;
  int wr = w >> 1, wc = w & 1;
  int g = l >> 4, c = l & 15;
  int by = blockIdx.x >> 5, bx = blockIdx.x & 31;
  const int rowB = by * 256, colB = bx * 128;

  // staging: pre-swizzled global source, linear LDS dest (rule #21)
  int srow = tid >> 2;
  int schunk = (tid & 3) ^ ((tid >> 3) & 3);
  const u16* gA0 = A + (size_t)(rowB + srow) * DIM + schunk * 8;
  const u16* gA1 = gA0 + (size_t)128 * DIM;
  const u16* gB0 = B + (size_t)(colB + srow) * DIM + schunk * 8;

#define STAGE(T, SL) do { size_t k_ = (size_t)(T) * BK;   \
    gload16(gA0 + k_, &lds[SL][0]    + tid * 8);          \
    gload16(gA1 + k_, &lds[SL][4096] + tid * 8);          \
    gload16(gB0 + k_, &lds[SL][8192] + tid * 8); } while (0)

  // fragment reads (swizzled): u16 idx = row*32 + (g ^ ((c>>1)&3))*8
  const int xc = (g ^ ((c >> 1) & 3)) * 8;

#define READ_A(AF, SL) do {                                                        \
    _Pragma("unroll") for (int mi_ = 0; mi_ < 4; ++mi_)                            \
      AF[mi_] = *(const bf16x8*)&lds[SL][(wr * 64 + mi_ * 16 + c) * 32 + xc]; } while (0)
#define READ_B(BF, SL) do {                                                        \
    _Pragma("unroll") for (int ni_ = 0; ni_ < 4; ++ni_)                            \
      BF[ni_] = *(const bf16x8*)&lds[SL][8192 + (wc * 64 + ni_ * 16 + c) * 32 + xc]; } while (0)

#define MMAC(AF, BF) do {                                                          \
    _Pragma("unroll") for (int mi_ = 0; mi_ < 4; ++mi_)                            \
      _Pragma("unroll") for (int ni_ = 0; ni_ < 4; ++ni_)                          \
        acc[mi_][ni_] = __builtin_amdgcn_mfma_f32_16x16x32_bf16(                   \
            AF[mi_], BF[ni_], acc[mi_][ni_], 0, 0, 0); } while (0)

  f32x4 acc[4][4] = {};
  bf16x8 a[4], bA[4], bB[4];

  // prologue: tiles 0,1 staged and landed; pre-read B of tile 0
  STAGE(0, 0); STAGE(1, 1);
  __syncthreads();
  READ_B(bA, 0);

  for (int kt = 0; kt < NT; kt += 2) {
    int s0 = kt % 3, s1 = (kt + 1) % 3, s2 = (kt + 2) % 3;
    // region kt: b_cur = bA
    if (kt + 2 < NT) STAGE(kt + 2, s2);
    READ_A(a, s0);
    READ_B(bB, s1);              // prefetch B(kt+1): overlaps MMAC below
    MMAC(a, bA);
    __syncthreads();
    // region kt+1: b_cur = bB
    if (kt + 3 < NT) STAGE(kt + 3, s0);   // (kt+3)%3 == s0; readers drained at sync
    READ_A(a, s1);
    if (kt + 2 < NT) READ_B(bA, s2);      // prefetch B(kt+2): landed at prev sync
    MMAC(a, bB);
    __syncthreads();
  }
#undef STAGE
#undef READ_A
#undef READ_B
#undef MMAC

  // --- epilogue: dist + fused hard-pos/neg partial select (R10-verified) ---
  float pc_[4]; int l2v[4]; int jcol[4];
#pragma unroll
  for (int ni = 0; ni < 4; ++ni) {
    int j = colB + wc * 64 + ni * 16 + c;
    jcol[ni] = j;
    l2v[ni] = lab2[j];
    pc_[ni] = sq2[j] - 2.0f * EPSV * s2[j];
  }
  const float cst = (float)DIM * EPSV * EPSV;
  int partCol = bx * 2 + wc;

#pragma unroll
  for (int mi = 0; mi < 4; ++mi) {
    float posV[4], negV[4]; int posI[4], negI[4];
    float pr[4]; int l1v[4];
#pragma unroll
    for (int r = 0; r < 4; ++r) {
      int i = rowB + wr * 64 + mi * 16 + g * 4 + r;
      l1v[r] = lab1[i];
      pr[r] = sq1[i] + 2.0f * EPSV * s1[i] + cst;
      posV[r] = -3.0e38f; posI[r] = 0x7fffffff;
      negV[r] =  3.0e38f; negI[r] = 0x7fffffff;
    }
#pragma unroll
    for (int ni = 0; ni < 4; ++ni) {
#pragma unroll
      for (int r = 0; r < 4; ++r) {
        float dot = acc[mi][ni][r];
        float d2 = pr[r] + pc_[ni] - 2.0f * dot;
        float dist = sqrtf(fmaxf(d2, 0.0f));
        bool same = (l1v[r] == l2v[ni]);
        float pv = same ? dist : -3.0e38f;
        float nv = same ?  3.0e38f : dist;
        if (pv > posV[r] || (pv == posV[r] && jcol[ni] < posI[r])) { posV[r] = pv; posI[r] = jcol[ni]; }
        if (nv < negV[r] || (nv == negV[r] && jcol[ni] < negI[r])) { negV[r] = nv; negI[r] = jcol[ni]; }
      }
    }
#pragma unroll
    for (int m = 1; m < 16; m <<= 1) {
#pragma unroll
      for (int r = 0; r < 4; ++r) {
        float ov = __shfl_xor(posV[r], m, 64);
        int   oi = __shfl_xor(posI[r], m, 64);
        if (ov > posV[r] || (ov == posV[r] && oi < posI[r])) { posV[r] = ov; posI[r] = oi; }
        float nv2 = __shfl_xor(negV[r], m, 64);
        int   on  = __shfl_xor(negI[r], m, 64);
        if (nv2 < negV[r] || (nv2 == negV[r] && on < negI[r])) { negV[r] = nv2; negI[r] = on; }
      }
    }
    if (c == 0) {
#pragma unroll
      for (int r = 0; r < 4; ++r) {
        int i = rowB + wr * 64 + mi * 16 + g * 4 + r;
        float4 o;
        o.x = posV[r]; o.y = __int_as_float(posI[r]);
        o.z = negV[r]; o.w = __int_as_float(negI[r]);
        part[(size_t)i * 64 + partCol] = o;
      }
    }
  }
}

// ---------------- combine 64 partials per row -> per-row loss directly ----------------
__global__ __launch_bounds__(256) void reduce_kernel(const float4* __restrict__ part,
                                                     float* __restrict__ perrow,
                                                     float* __restrict__ validf) {
  int row = blockIdx.x * 4 + (threadIdx.x >> 6);
  int lane = threadIdx.x & 63;
  float4 p = part[(size_t)row * 64 + lane];
  float posV = p.x; int posI = __float_as_int(p.y);
  float negV = p.z; int negI = __float_as_int(p.w);
#pragma unroll
  for (int m = 1; m < 64; m <<= 1) {
    float ov = __shfl_xor(posV, m, 64);
    int   oi = __shfl_xor(posI, m, 64);
    if (ov > posV || (ov == posV && oi < posI)) { posV = ov; posI = oi; }
    float nv = __shfl_xor(negV, m, 64);
    int   on = __shfl_xor(negI, m, 64);
    if (nv < negV || (nv == negV && on < negI)) { negV = nv; negI = on; }
  }
  if (lane == 0) {
    bool valid = (posV > -1.0e38f && negV < 1.0e38f);
    perrow[row] = valid ? fmaxf(posV - negV, 0.0f) : 0.0f;
    validf[row] = valid ? 1.0f : 0.0f;
  }
}

// ---------------- deterministic finalize (fixed-order tree) ----------------
__global__ __launch_bounds__(256) void finalize_kernel(const float* __restrict__ perrow,
                                                       const float* __restrict__ validf,
                                                       float* __restrict__ out) {
  int t = threadIdx.x;
  float s = 0.f, cv = 0.f;
  for (int i = t; i < BS; i += 256) { s += perrow[i]; cv += validf[i]; }
  __shared__ float ls[256], lc[256];
  ls[t] = s; lc[t] = cv;
  __syncthreads();
  for (int m = 128; m; m >>= 1) {
    if (t < m) { ls[t] += ls[t + m]; lc[t] += lc[t + m]; }
    __syncthreads();
  }
  if (t == 0) out[0] = (lc[0] > 0.f) ? ls[0] / fmaxf(lc[0], 1.f) : 0.f;
}

extern "C" void kernel_launch(void* const* d_in, const int* in_sizes, int n_in,
                              void* d_out, int out_size, void* d_ws, size_t ws_size,
                              hipStream_t stream) {
  const float* h1 = (const float*)d_in[0];
  const float* h2 = (const float*)d_in[1];
  const int* lab1 = (const int*)d_in[2];
  const int* lab2 = (const int*)d_in[3];

  char* ws = (char*)d_ws;
  u16* A = (u16*)ws;
  u16* B = (u16*)(ws + (size_t)BS * DIM * 2);
  size_t off = (size_t)BS * DIM * 4;
  float* sq1 = (float*)(ws + off); off += BS * 4;
  float* s1  = (float*)(ws + off); off += BS * 4;
  float* sq2 = (float*)(ws + off); off += BS * 4;
  float* s2  = (float*)(ws + off); off += BS * 4;
  float4* part = (float4*)(ws + off); off += (size_t)BS * 64 * 16;
  float* perrow = (float*)(ws + off); off += BS * 4;
  float* validf = (float*)(ws + off); off += BS * 4;

  prep_kernel<<<2 * BS, 256, 0, stream>>>(h1, h2, A, B, sq1, s1, sq2, s2);
  gemm_select_kernel<<<512, 512, 0, stream>>>(A, B, sq1, s1, sq2, s2, lab1, lab2, part);
  reduce_kernel<<<BS / 4, 256, 0, stream>>>(part, perrow, validf);
  finalize_kernel<<<1, 256, 0, stream>>>(perrow, validf, (float*)d_out);
}